// Round 1
// baseline (809.923 us; speedup 1.0000x reference)
//
#include <hip/hip_runtime.h>

// Problem constants (match reference)
#define BATCH 32
#define T_IN 1024
#define TP 1025      // T+1 (phoneme + silence token)
#define EMB 384
#define GROUPS 4
#define GC 96        // channels per group
#define TT 64        // conv t-tile per block

// ---------------------------------------------------------------------------
// Kernel 1: per-batch inclusive cumsum of durations (1025 ints), one wave/batch
// ---------------------------------------------------------------------------
__global__ __launch_bounds__(64) void scan_kernel(const int* __restrict__ dur,
                                                  int* __restrict__ cum) {
    const int b = blockIdx.x;
    const int l = threadIdx.x;
    const int* d = dur + b * TP;
    int* c = cum + b * TP;
    const int base = l * 17;  // 64*17 = 1088 >= 1025
    int vals[17];
    int run = 0;
#pragma unroll
    for (int m = 0; m < 17; ++m) {
        int idx = base + m;
        int v = (idx < TP) ? d[idx] : 0;
        run += v;
        vals[m] = run;  // inclusive within lane
    }
    const int mysum = run;
    int pref = run;
    // inclusive scan across 64 lanes
    for (int off = 1; off < 64; off <<= 1) {
        int n = __shfl_up(pref, off, 64);
        if (l >= off) pref += n;
    }
    const int excl = pref - mysum;
#pragma unroll
    for (int m = 0; m < 17; ++m) {
        int idx = base + m;
        if (idx < TP) c[idx] = excl + vals[m];
    }
}

// ---------------------------------------------------------------------------
// Kernel 2: init durations_pred to conv2 bias (atomics accumulate onto it)
// ---------------------------------------------------------------------------
__global__ __launch_bounds__(256) void init_pred_kernel(const float* __restrict__ b2,
                                                        float* __restrict__ pred) {
    int i = blockIdx.x * 256 + threadIdx.x;
    if (i < BATCH * TP) pred[i] = b2[0];
}

// ---------------------------------------------------------------------------
// Kernel 3: grouped conv (k=3, pad 1) + ReLU + 1x1 conv, fp32 vector.
// grid = (17 t-tiles, 4 groups, 32 batches), block = 256.
// Thread (tc = tid&15, tt = tid>>4): channels c = tc*6..tc*6+5 (within group),
// t = t0 + tt + 16*j, j = 0..3.  LDS x-tile stride 97 (96 % 32 == 0 would be a
// 16-way bank conflict; 97 % 32 == 1 is conflict-free).
// ---------------------------------------------------------------------------
__global__ __launch_bounds__(256) void conv_kernel(const float* __restrict__ phoneme,
                                                   const float* __restrict__ silence,
                                                   const float* __restrict__ w1,
                                                   const float* __restrict__ b1,
                                                   const float* __restrict__ w2,
                                                   float* __restrict__ pred) {
    const int tile = blockIdx.x;
    const int g = blockIdx.y;
    const int b = blockIdx.z;
    const int t0 = tile * TT;

    __shared__ float xs[TT + 2][GC + 1];   // rows t0-1 .. t0+TT, padded stride 97
    __shared__ float red[4][16][16];       // [j][tt][tc]

    const int tid = threadIdx.x;

    // Stage x-tile: (TT+2) rows x 96 ch of ph[b, :, g*96..] (ph row 1024 = silence)
    for (int e = tid; e < (TT + 2) * (GC / 4); e += 256) {
        int row = e / (GC / 4);
        int v = e % (GC / 4);
        int r = t0 - 1 + row;
        float4 val;
        if (r < 0 || r > T_IN) {
            val = make_float4(0.f, 0.f, 0.f, 0.f);
        } else if (r == T_IN) {
            const float4* s4 = (const float4*)(silence + g * GC);
            val = s4[v];
        } else {
            const float4* p4 =
                (const float4*)(phoneme + ((size_t)(b * T_IN + r)) * EMB + g * GC);
            val = p4[v];
        }
        float* dst = &xs[row][v * 4];
        dst[0] = val.x; dst[1] = val.y; dst[2] = val.z; dst[3] = val.w;
    }
    __syncthreads();

    const int tc = tid & 15;   // channel sub-tile: c = tc*6 .. tc*6+5
    const int tt = tid >> 4;   // t sub-tile: t_local = tt + 16*j

    float acc[6][4];
#pragma unroll
    for (int cc = 0; cc < 6; ++cc)
#pragma unroll
        for (int j = 0; j < 4; ++j) acc[cc][j] = 0.f;

    // w1 layout: [oc][ic][k], oc = g*96 + tc*6 + cc
    const float* wg = w1 + (size_t)(g * GC + tc * 6) * (GC * 3);

    for (int i = 0; i < GC; ++i) {
        float x[3][4];
#pragma unroll
        for (int k = 0; k < 3; ++k)
#pragma unroll
            for (int j = 0; j < 4; ++j) x[k][j] = xs[tt + 16 * j + k][i];
#pragma unroll
        for (int cc = 0; cc < 6; ++cc) {
            const float* wp = wg + cc * (GC * 3) + i * 3;
            float w0 = wp[0], w1v = wp[1], w2v = wp[2];
#pragma unroll
            for (int j = 0; j < 4; ++j)
                acc[cc][j] += w0 * x[0][j] + w1v * x[1][j] + w2v * x[2][j];
        }
    }

    // bias + ReLU + dot with conv2 weight, partial over this thread's 6 channels
    float bsum[4] = {0.f, 0.f, 0.f, 0.f};
#pragma unroll
    for (int cc = 0; cc < 6; ++cc) {
        int c = g * GC + tc * 6 + cc;
        float bias = b1[c];
        float wc = w2[c];
#pragma unroll
        for (int j = 0; j < 4; ++j) {
            float h = acc[cc][j] + bias;
            h = h > 0.f ? h : 0.f;
            bsum[j] += wc * h;
        }
    }
#pragma unroll
    for (int j = 0; j < 4; ++j) red[j][tt][tc] = bsum[j];
    __syncthreads();

    if (tid < 64) {
        int j = tid >> 4, t_sub = tid & 15;
        float s = 0.f;
#pragma unroll
        for (int c = 0; c < 16; ++c) s += red[j][t_sub][c];
        int t = t0 + t_sub + 16 * j;
        if (t < TP) atomicAdd(&pred[b * TP + t], s);
    }
}

// ---------------------------------------------------------------------------
// Kernel 4: length-regulate gather. grid = (ceil(t_out/8), 32), block = 256.
// 8 frames/block: threads 0..7 binary-search cum, then block streams 768
// float4 (perfectly contiguous stores).
// ---------------------------------------------------------------------------
__global__ __launch_bounds__(256) void gather_kernel(const float* __restrict__ phoneme,
                                                     const float* __restrict__ silence,
                                                     const int* __restrict__ cum,
                                                     float* __restrict__ out,
                                                     int t_out) {
    const int b = blockIdx.y;
    const int f0 = blockIdx.x * 8;
    const int tid = threadIdx.x;

    __shared__ int sidx[8];
    __shared__ int stotal;

    if (tid == 0) stotal = cum[b * TP + T_IN];
    if (tid < 8) {
        int t = f0 + tid;
        int id = -1;
        if (t < t_out) {
            const int* c = cum + b * TP;
            int lo = 0, hi = TP;
            while (lo < hi) {
                int mid = (lo + hi) >> 1;
                if (c[mid] <= t) lo = mid + 1; else hi = mid;
            }
            id = lo > T_IN ? T_IN : lo;
        }
        sidx[tid] = id;
    }
    __syncthreads();

    const int total = stotal;
    const float4* ph4 = (const float4*)phoneme;
    const float4* s4 = (const float4*)silence;
    float4* out4 = (float4*)out;

    for (int e = tid; e < 8 * (EMB / 4); e += 256) {
        int fl = e / (EMB / 4);
        int v = e % (EMB / 4);
        int t = f0 + fl;
        if (t >= t_out) continue;
        float4 val;
        if (t >= total) {
            val = make_float4(0.f, 0.f, 0.f, 0.f);
        } else {
            int id = sidx[fl];
            val = (id == T_IN) ? s4[v] : ph4[(size_t)(b * T_IN + id) * (EMB / 4) + v];
        }
        out4[((size_t)b * t_out + t) * (EMB / 4) + v] = val;
    }
}

// ---------------------------------------------------------------------------
extern "C" void kernel_launch(void* const* d_in, const int* in_sizes, int n_in,
                              void* d_out, int out_size, void* d_ws, size_t ws_size,
                              hipStream_t stream) {
    const float* phoneme = (const float*)d_in[0];
    const float* silence = (const float*)d_in[1];
    const float* conv1_w = (const float*)d_in[2];
    const float* conv1_b = (const float*)d_in[3];
    const float* conv2_w = (const float*)d_in[4];
    const float* conv2_b = (const float*)d_in[5];
    const int* durations = (const int*)d_in[6];
    // d_in[7] = t_out on device; derive it from out_size instead (host-side).
    const int t_out = (out_size - BATCH * TP) / (BATCH * EMB);

    float* out_expanded = (float*)d_out;                           // [B, t_out, EMB]
    float* out_pred = (float*)d_out + (size_t)BATCH * t_out * EMB; // [B, TP]
    int* cum = (int*)d_ws;                                         // [B, TP] ints

    scan_kernel<<<BATCH, 64, 0, stream>>>(durations, cum);
    init_pred_kernel<<<(BATCH * TP + 255) / 256, 256, 0, stream>>>(conv2_b, out_pred);
    conv_kernel<<<dim3((TP + TT - 1) / TT, GROUPS, BATCH), 256, 0, stream>>>(
        phoneme, silence, conv1_w, conv1_b, conv2_w, out_pred);
    gather_kernel<<<dim3((t_out + 7) / 8, BATCH), 256, 0, stream>>>(
        phoneme, silence, cum, out_expanded, t_out);
}

// Round 2
// 263.503 us; speedup vs baseline: 3.0737x; 3.0737x over previous
//
#include <hip/hip_runtime.h>

// Problem constants (match reference)
#define BATCH 32
#define T_IN 1024
#define TP 1025      // T+1 (phoneme + silence token)
#define EMB 384
#define GROUPS 4
#define GC 96        // channels per group
#define KDIM 288     // GC * 3 taps (im2col K), 9 ksteps of 32

typedef __attribute__((ext_vector_type(8))) short short8;   // 8 bf16 (4 VGPRs)
typedef __attribute__((ext_vector_type(4))) float f32x4;    // 4 fp32 acc

#define N_WPACK (GROUPS * 9 * 6 * 64 * 8)   // 110592 bf16 elements

__device__ __forceinline__ unsigned short f2bf(float f) {
    union { float f; unsigned u; } v; v.f = f;
    unsigned u = v.u + 0x7fffu + ((v.u >> 16) & 1u);  // RNE
    return (unsigned short)(u >> 16);
}

// ---------------------------------------------------------------------------
// Kernel 0 (prep): pack w1 -> bf16 MFMA B-fragment layout; init pred to b2.
// wpack[g][ks][nt][lane][j] = bf16(w1[g*96 + nt*16 + (lane&15)][ic][k]),
//   kk = ks*32 + (lane>>4)*8 + j, k = kk/96, ic = kk%96
// ---------------------------------------------------------------------------
__global__ __launch_bounds__(256) void prep_kernel(const float* __restrict__ w1,
                                                   const float* __restrict__ b2,
                                                   unsigned short* __restrict__ wpack,
                                                   float* __restrict__ pred) {
    int i = blockIdx.x * 256 + threadIdx.x;
    if (i < N_WPACK) {
        int j = i & 7;
        int lane = (i >> 3) & 63;
        int rest = i >> 9;
        int nt = rest % 6; rest /= 6;
        int ks = rest % 9;
        int g = rest / 9;
        int oc = nt * 16 + (lane & 15);
        int kk = ks * 32 + (lane >> 4) * 8 + j;
        int k = kk / 96, ic = kk % 96;
        float v = w1[((size_t)(g * GC + oc) * GC + ic) * 3 + k];
        wpack[i] = f2bf(v);
    }
    if (i < BATCH * TP) pred[i] = b2[0];
}

// ---------------------------------------------------------------------------
// Kernel 1: per-batch inclusive cumsum, coalesced rounds, one wave/batch
// ---------------------------------------------------------------------------
__global__ __launch_bounds__(64) void scan_kernel(const int* __restrict__ dur,
                                                  int* __restrict__ cum) {
    const int b = blockIdx.x;
    const int l = threadIdx.x;
    const int* d = dur + b * TP;
    int* c = cum + b * TP;
    int offset = 0;
    for (int r = 0; r < 17; ++r) {
        int idx = r * 64 + l;
        int v = (idx < TP) ? d[idx] : 0;
        int s = v;
#pragma unroll
        for (int off = 1; off < 64; off <<= 1) {
            int n = __shfl_up(s, off, 64);
            if (l >= off) s += n;
        }
        if (idx < TP) c[idx] = s + offset;
        offset += __shfl(s, 63, 64);
    }
}

// ---------------------------------------------------------------------------
// Kernel 2: grouped conv (k=3,pad 1) + ReLU + 1x1 conv via bf16 MFMA.
// grid = (17 t-tiles of 64, 4 groups, 32 batches), block = 256 (4 waves).
// Wave w computes rows t0+w*16..+15 x all 96 oc of its group:
//   per kstep: 1 ds_read_b128 A-frag + 6 global 16B B-frags + 6 MFMAs.
// A-frag: A[m=lane&15][kk=quad*8+j] ; kk->(k=kk/96, ic=kk%96); 96%32==0 so
// k is kstep-uniform. LDS row stride 104 bf16 = 208 B (16B-aligned; 52-dword
// stride -> 2 rows/bank = free 2-way).
// ---------------------------------------------------------------------------
__global__ __launch_bounds__(256) void conv_mfma_kernel(const float* __restrict__ phoneme,
                                                        const float* __restrict__ silence,
                                                        const float* __restrict__ b1,
                                                        const float* __restrict__ w2,
                                                        const unsigned short* __restrict__ wpack,
                                                        float* __restrict__ pred) {
    const int tile = blockIdx.x;
    const int g = blockIdx.y;
    const int b = blockIdx.z;
    const int t0 = tile * 64;

    __shared__ __align__(16) unsigned short xs[66][104];  // rows t0-1..t0+64, bf16
    __shared__ float red[4][16][17];

    const int tid = threadIdx.x;

    // Stage x-tile (fp32 -> bf16): 66 rows x 96 ch of ph[b, :, g*96..]
    for (int e = tid; e < 66 * 24; e += 256) {
        int row = e / 24;
        int v = e - row * 24;
        int r = t0 - 1 + row;
        float4 val;
        if (r < 0 || r > T_IN) {
            val = make_float4(0.f, 0.f, 0.f, 0.f);
        } else if (r == T_IN) {
            val = *(const float4*)(silence + g * GC + v * 4);
        } else {
            val = *(const float4*)(phoneme + ((size_t)(b * T_IN + r)) * EMB + g * GC + v * 4);
        }
        ushort4 pk;
        pk.x = f2bf(val.x); pk.y = f2bf(val.y); pk.z = f2bf(val.z); pk.w = f2bf(val.w);
        *(ushort4*)&xs[row][v * 4] = pk;
    }
    __syncthreads();

    const int w = tid >> 6;
    const int lane = tid & 63;
    const int quad = lane >> 4;
    const int lr = lane & 15;

    f32x4 acc[6];
#pragma unroll
    for (int nt = 0; nt < 6; ++nt) acc[nt] = (f32x4){0.f, 0.f, 0.f, 0.f};

    const unsigned short* wg = wpack + (size_t)g * 9 * 6 * 512;

#pragma unroll
    for (int ks = 0; ks < 9; ++ks) {
        const int k = ks / 3;                       // tap index (kstep-uniform)
        const int icoff = 32 * (ks % 3) + quad * 8; // ic offset within group
        const int lrow = w * 16 + lr + k;           // LDS row (t0-1 origin)
        short8 a = *(const short8*)&xs[lrow][icoff];
#pragma unroll
        for (int nt = 0; nt < 6; ++nt) {
            short8 bf = *(const short8*)(wg + ((size_t)(ks * 6 + nt) * 64 + lane) * 8);
            acc[nt] = __builtin_amdgcn_mfma_f32_16x16x32_bf16(a, bf, acc[nt], 0, 0, 0);
        }
    }

    // Epilogue: bias + ReLU + w2-weighted partial sum over this lane's oc
    // D layout: row(m) = quad*4+reg, col(oc) = lane&15  [m89/m91 verified]
    float s[4] = {0.f, 0.f, 0.f, 0.f};
#pragma unroll
    for (int nt = 0; nt < 6; ++nt) {
        int oc = g * GC + nt * 16 + lr;
        float bias = b1[oc];
        float wc = w2[oc];
#pragma unroll
        for (int reg = 0; reg < 4; ++reg) {
            float h = acc[nt][reg] + bias;
            h = h > 0.f ? h : 0.f;
            s[reg] += wc * h;
        }
    }
#pragma unroll
    for (int reg = 0; reg < 4; ++reg) red[w][quad * 4 + reg][lr] = s[reg];
    __syncthreads();

    if (tid < 64) {
        int wv = tid >> 4, m = tid & 15;
        float sum = 0.f;
#pragma unroll
        for (int c2 = 0; c2 < 16; ++c2) sum += red[wv][m][c2];
        int t = t0 + wv * 16 + m;
        if (t < TP) atomicAdd(pred + b * TP + t, sum);
    }
}

// ---------------------------------------------------------------------------
// Kernel 3: length-regulate gather. grid = (ceil(t_out/64), 32), block = 256.
// 64 parallel binary searches (wave 0+..), then stream 64x96 float4.
// ---------------------------------------------------------------------------
__global__ __launch_bounds__(256) void gather_kernel(const float* __restrict__ phoneme,
                                                     const float* __restrict__ silence,
                                                     const int* __restrict__ cum,
                                                     float* __restrict__ out,
                                                     int t_out) {
    const int b = blockIdx.y;
    const int f0 = blockIdx.x * 64;
    const int tid = threadIdx.x;

    __shared__ int sidx[64];
    __shared__ int stotal;

    if (tid == 0) stotal = cum[b * TP + T_IN];
    if (tid < 64) {
        int t = f0 + tid;
        int id = 0;
        if (t < t_out) {
            const int* c = cum + b * TP;
            int lo = 0, hi = TP;
            while (lo < hi) {
                int mid = (lo + hi) >> 1;
                if (c[mid] <= t) lo = mid + 1; else hi = mid;
            }
            id = lo > T_IN ? T_IN : lo;
        }
        sidx[tid] = id;
    }
    __syncthreads();

    const int total = stotal;
    const float4* ph4 = (const float4*)phoneme;
    const float4* s4 = (const float4*)silence;
    float4* out4 = (float4*)out;

    for (int e = tid; e < 64 * 96; e += 256) {
        int fl = e / 96;
        int v = e - fl * 96;
        int t = f0 + fl;
        if (t >= t_out) continue;
        float4 val;
        if (t >= total) {
            val = make_float4(0.f, 0.f, 0.f, 0.f);
        } else {
            int id = sidx[fl];
            val = (id == T_IN) ? s4[v] : ph4[((size_t)(b * T_IN) + id) * 96 + v];
        }
        out4[((size_t)b * t_out + t) * 96 + v] = val;
    }
}

// ---------------------------------------------------------------------------
extern "C" void kernel_launch(void* const* d_in, const int* in_sizes, int n_in,
                              void* d_out, int out_size, void* d_ws, size_t ws_size,
                              hipStream_t stream) {
    const float* phoneme = (const float*)d_in[0];
    const float* silence = (const float*)d_in[1];
    const float* conv1_w = (const float*)d_in[2];
    const float* conv1_b = (const float*)d_in[3];
    const float* conv2_w = (const float*)d_in[4];
    const float* conv2_b = (const float*)d_in[5];
    const int* durations = (const int*)d_in[6];
    // d_in[7] = t_out on device; derive from out_size host-side instead.
    const int t_out = (out_size - BATCH * TP) / (BATCH * EMB);

    float* out_expanded = (float*)d_out;                            // [B, t_out, EMB]
    float* out_pred = (float*)d_out + (size_t)BATCH * t_out * EMB;  // [B, TP]

    int* cum = (int*)d_ws;                                          // 131200 B
    unsigned short* wpack = (unsigned short*)((char*)d_ws + 131200); // 221184 B, 16B-aligned

    prep_kernel<<<(N_WPACK + 255) / 256, 256, 0, stream>>>(conv1_w, conv2_b, wpack, out_pred);
    scan_kernel<<<BATCH, 64, 0, stream>>>(durations, cum);
    conv_mfma_kernel<<<dim3(17, GROUPS, BATCH), 256, 0, stream>>>(
        phoneme, silence, conv1_b, conv2_w, wpack, out_pred);
    gather_kernel<<<dim3((t_out + 63) / 64, BATCH), 256, 0, stream>>>(
        phoneme, silence, cum, out_expanded, t_out);
}